// Round 1
// baseline (510.835 us; speedup 1.0000x reference)
//
#include <hip/hip_runtime.h>
#include <math.h>

#define N 1024
#define NN (N*N)
#define NE 32768

// ---------------- workspace layout (in floats) ----------------
#define OFF_A0   ((size_t)0)
#define OFF_A1   ((size_t)(2*NN))
#define OFF_M0   ((size_t)(5*NN))
#define OFF_M1   ((size_t)(6*NN))
#define OFF_BT   ((size_t)(7*NN))
#define OFF_AN   ((size_t)(8*NN))
#define OFF_H1   ((size_t)(9*NN))                  // 16*512*512 = 4*NN
#define OFF_H2   ((size_t)(13*NN))                 // 4*257*257 = 264196
#define OFF_H3   (OFF_H2 + 264196)                 // 16*514*514 = 4227136
#define OFF_DINV (OFF_H3 + 4227136)
#define OFF_DFLG (OFF_DINV + 1024)
#define OFF_XW1  (OFF_DFLG + 1024)                 // 1024*64
#define OFF_HB   (OFF_XW1 + 65536)                 // 1024*64
#define OFF_HW2  (OFF_HB + 65536)                  // 1024*32

// ---------------- edge scatter ----------------
__global__ void k_scatter(const int* __restrict__ e, float* __restrict__ A) {
  int k = blockIdx.x * blockDim.x + threadIdx.x;
  if (k < NE) atomicAdd(&A[e[k] * N + e[NE + k]], 1.0f);
}

// ---------------- conv1 (pad=1) + relu + maxpool2 : LxNxN -> 16x512x512 ----------------
template<int L>
__global__ __launch_bounds__(256) void k_conv1_pool(const float* __restrict__ A,
    const float* __restrict__ W, const float* __restrict__ Bn, float* __restrict__ out) {
  __shared__ float sW[16 * L * 9];
  __shared__ float sB[16];
  int tid = threadIdx.y * 16 + threadIdx.x;
  for (int i = tid; i < 16 * L * 9; i += 256) sW[i] = W[i];
  if (tid < 16) sB[tid] = Bn[tid];
  __syncthreads();
  int ox = blockIdx.x * 16 + threadIdx.x;
  int oy = blockIdx.y * 16 + threadIdx.y;
  float p[L][4][4];
  #pragma unroll
  for (int l = 0; l < L; ++l)
    #pragma unroll
    for (int r = 0; r < 4; ++r) {
      int iy = 2 * oy - 1 + r;
      #pragma unroll
      for (int c = 0; c < 4; ++c) {
        int ix = 2 * ox - 1 + c;
        p[l][r][c] = (iy >= 0 && iy < N && ix >= 0 && ix < N) ? A[(size_t)l * NN + (size_t)iy * N + ix] : 0.f;
      }
    }
  for (int oc = 0; oc < 16; ++oc) {
    float wr[L * 9];
    #pragma unroll
    for (int t = 0; t < L * 9; ++t) wr[t] = sW[oc * L * 9 + t];
    float b = sB[oc];
    float m = 0.f;
    #pragma unroll
    for (int dy = 0; dy < 2; ++dy)
      #pragma unroll
      for (int dx = 0; dx < 2; ++dx) {
        float s = b;
        #pragma unroll
        for (int l = 0; l < L; ++l)
          #pragma unroll
          for (int ky = 0; ky < 3; ++ky)
            #pragma unroll
            for (int kx = 0; kx < 3; ++kx)
              s = fmaf(p[l][dy + ky][dx + kx], wr[l * 9 + ky * 3 + kx], s);
        m = fmaxf(m, s);  // relu folded into max (m starts at 0)
      }
    out[(size_t)oc * 512 * 512 + (size_t)oy * 512 + ox] = m;
  }
}

// ---------------- conv2 (pad=2) + relu + maxpool2 : 16x512x512 -> 4x257x257 ----------------
__global__ __launch_bounds__(256) void k_conv2_pool(const float* __restrict__ in,
    const float* __restrict__ W, const float* __restrict__ Bn, float* __restrict__ out) {
  __shared__ float sW[4 * 16 * 9];
  __shared__ float sB[4];
  int tid = threadIdx.y * 16 + threadIdx.x;
  for (int i = tid; i < 4 * 16 * 9; i += 256) sW[i] = W[i];
  if (tid < 4) sB[tid] = Bn[tid];
  __syncthreads();
  int ox = blockIdx.x * 16 + threadIdx.x;
  int oy = blockIdx.y * 16 + threadIdx.y;
  if (ox >= 257 || oy >= 257) return;
  float acc[4][2][2];
  #pragma unroll
  for (int oc = 0; oc < 4; ++oc)
    #pragma unroll
    for (int dy = 0; dy < 2; ++dy)
      #pragma unroll
      for (int dx = 0; dx < 2; ++dx) acc[oc][dy][dx] = sB[oc];
  for (int ic = 0; ic < 16; ++ic) {
    float p[4][4];
    #pragma unroll
    for (int r = 0; r < 4; ++r) {
      int iy = 2 * oy - 2 + r;
      #pragma unroll
      for (int c = 0; c < 4; ++c) {
        int ix = 2 * ox - 2 + c;
        p[r][c] = (iy >= 0 && iy < 512 && ix >= 0 && ix < 512) ? in[(size_t)ic * 512 * 512 + (size_t)iy * 512 + ix] : 0.f;
      }
    }
    #pragma unroll
    for (int oc = 0; oc < 4; ++oc)
      #pragma unroll
      for (int ky = 0; ky < 3; ++ky)
        #pragma unroll
        for (int kx = 0; kx < 3; ++kx) {
          float w = sW[oc * 144 + ic * 9 + ky * 3 + kx];
          #pragma unroll
          for (int dy = 0; dy < 2; ++dy)
            #pragma unroll
            for (int dx = 0; dx < 2; ++dx)
              acc[oc][dy][dx] = fmaf(p[dy + ky][dx + kx], w, acc[oc][dy][dx]);
        }
  }
  #pragma unroll
  for (int oc = 0; oc < 4; ++oc) {
    float m = 0.f;
    #pragma unroll
    for (int dy = 0; dy < 2; ++dy)
      #pragma unroll
      for (int dx = 0; dx < 2; ++dx) m = fmaxf(m, acc[oc][dy][dx]);
    out[(size_t)oc * 257 * 257 + (size_t)oy * 257 + ox] = m;
  }
}

// ---------------- tconv1 (k=2,s=2) + relu : 4x257x257 -> 16x514x514 (flipped weights) ----------------
__global__ __launch_bounds__(256) void k_tconv1(const float* __restrict__ in,
    const float* __restrict__ W, const float* __restrict__ Bn, float* __restrict__ out) {
  __shared__ float sW[16 * 4 * 4];
  __shared__ float sB[16];
  int tid = threadIdx.y * 16 + threadIdx.x;
  for (int i = tid; i < 256; i += 256) sW[i] = W[i];
  if (tid < 16) sB[tid] = Bn[tid];
  __syncthreads();
  int n = blockIdx.x * 16 + threadIdx.x;
  int m = blockIdx.y * 16 + threadIdx.y;
  if (n >= 257 || m >= 257) return;
  float v[4];
  #pragma unroll
  for (int c = 0; c < 4; ++c) v[c] = in[(size_t)c * 257 * 257 + (size_t)m * 257 + n];
  for (int oc = 0; oc < 16; ++oc) {
    #pragma unroll
    for (int dy = 0; dy < 2; ++dy)
      #pragma unroll
      for (int dx = 0; dx < 2; ++dx) {
        float s = sB[oc];
        #pragma unroll
        for (int c = 0; c < 4; ++c)
          s = fmaf(v[c], sW[oc * 16 + c * 4 + (1 - dy) * 2 + (1 - dx)], s);
        out[(size_t)oc * 514 * 514 + (size_t)(2 * m + dy) * 514 + (2 * n + dx)] = fmaxf(s, 0.f);
      }
  }
}

// ---------------- tconv2 (k=2,s=2) + sigmoid, crop to NxN, attended = A*att in-place ----------------
template<int L>
__global__ __launch_bounds__(256) void k_tconv2_sig(const float* __restrict__ h3,
    const float* __restrict__ W, const float* __restrict__ Bn, float* __restrict__ A) {
  __shared__ float sW[L * 16 * 4];
  __shared__ float sB[L];
  int tid = threadIdx.y * 16 + threadIdx.x;
  for (int i = tid; i < L * 64; i += 256) sW[i] = W[i];
  if (tid < L) sB[tid] = Bn[tid];
  __syncthreads();
  int n = blockIdx.x * 16 + threadIdx.x;   // 0..511
  int m = blockIdx.y * 16 + threadIdx.y;   // 0..511
  float v[16];
  #pragma unroll
  for (int c = 0; c < 16; ++c) v[c] = h3[(size_t)c * 514 * 514 + (size_t)m * 514 + n];
  #pragma unroll
  for (int l = 0; l < L; ++l) {
    #pragma unroll
    for (int dy = 0; dy < 2; ++dy)
      #pragma unroll
      for (int dx = 0; dx < 2; ++dx) {
        float s = sB[l];
        #pragma unroll
        for (int c = 0; c < 16; ++c)
          s = fmaf(v[c], sW[l * 64 + c * 4 + (1 - dy) * 2 + (1 - dx)], s);
        float sg = 1.f / (1.f + expf(-s));
        size_t idx = (size_t)l * NN + (size_t)(2 * m + dy) * N + (2 * n + dx);
        A[idx] *= sg;
      }
  }
}

// ---------------- gcn_norm: deg/dinv then scale ----------------
__global__ __launch_bounds__(256) void k_deg(const float* __restrict__ B,
    float* __restrict__ dinv, float* __restrict__ dflag) {
  const int row = blockIdx.x;
  const float* r = B + (size_t)row * N;
  float s = 0.f;
  for (int j = threadIdx.x; j < N; j += 256) s += r[j];
  #pragma unroll
  for (int o = 32; o > 0; o >>= 1) s += __shfl_down(s, o, 64);
  __shared__ float red[4];
  if ((threadIdx.x & 63) == 0) red[threadIdx.x >> 6] = s;
  __syncthreads();
  if (threadIdx.x == 0) {
    float tot = red[0] + red[1] + red[2] + red[3];
    float d = r[row];
    float fl = (d == 0.0f) ? 1.0f : 0.0f;
    float deg = tot + fl;
    dinv[row] = (deg > 0.0f) ? (1.0f / sqrtf(deg)) : 0.0f;
    dflag[row] = fl;
  }
}

__global__ __launch_bounds__(256) void k_scale(const float* __restrict__ B,
    const float* __restrict__ dinv, const float* __restrict__ dflag, float* __restrict__ out) {
  int idx = blockIdx.x * 256 + threadIdx.x;
  int i = idx >> 10, j = idx & 1023;
  float v = B[idx];
  if (i == j) v += dflag[i];
  out[idx] = v * dinv[i] * dinv[j];
}

__global__ __launch_bounds__(256) void k_max(const float* __restrict__ a,
    const float* __restrict__ b, float* __restrict__ o) {
  int i = blockIdx.x * 256 + threadIdx.x;
  o[i] = fmaxf(a[i], b[i]);
}

// ---------------- 1024^3 f32 matmul: C = A @ B ----------------
__global__ __launch_bounds__(256) void k_mm1024(const float* __restrict__ A,
    const float* __restrict__ B, float* __restrict__ C) {
  __shared__ float As[16][68];
  __shared__ float Bs[16][68];
  const int tid = threadIdx.x;
  const int tx = tid & 15, ty = tid >> 4;
  const int bm = blockIdx.y << 6, bn = blockIdx.x << 6;
  const int lm = tid >> 2;         // 0..63
  const int lk = (tid & 3) << 2;   // 0,4,8,12
  const int lbk = tid >> 6;        // 0..3
  const int lbn = tid & 63;        // 0..63
  float acc[4][4] = {{0.f}};
  float4 av = *(const float4*)&A[(size_t)(bm + lm) * N + lk];
  float bv[4];
  #pragma unroll
  for (int r = 0; r < 4; ++r) bv[r] = B[(size_t)(lbk + 4 * r) * N + bn + lbn];
  for (int k0 = 0; k0 < N; k0 += 16) {
    __syncthreads();
    As[lk + 0][lm] = av.x; As[lk + 1][lm] = av.y; As[lk + 2][lm] = av.z; As[lk + 3][lm] = av.w;
    #pragma unroll
    for (int r = 0; r < 4; ++r) Bs[lbk + 4 * r][lbn] = bv[r];
    __syncthreads();
    if (k0 + 16 < N) {
      av = *(const float4*)&A[(size_t)(bm + lm) * N + k0 + 16 + lk];
      #pragma unroll
      for (int r = 0; r < 4; ++r) bv[r] = B[(size_t)(k0 + 16 + lbk + 4 * r) * N + bn + lbn];
    }
    #pragma unroll
    for (int kk = 0; kk < 16; ++kk) {
      float4 a = *(const float4*)&As[kk][ty << 2];
      float4 b = *(const float4*)&Bs[kk][tx << 2];
      acc[0][0] = fmaf(a.x, b.x, acc[0][0]); acc[0][1] = fmaf(a.x, b.y, acc[0][1]);
      acc[0][2] = fmaf(a.x, b.z, acc[0][2]); acc[0][3] = fmaf(a.x, b.w, acc[0][3]);
      acc[1][0] = fmaf(a.y, b.x, acc[1][0]); acc[1][1] = fmaf(a.y, b.y, acc[1][1]);
      acc[1][2] = fmaf(a.y, b.z, acc[1][2]); acc[1][3] = fmaf(a.y, b.w, acc[1][3]);
      acc[2][0] = fmaf(a.z, b.x, acc[2][0]); acc[2][1] = fmaf(a.z, b.y, acc[2][1]);
      acc[2][2] = fmaf(a.z, b.z, acc[2][2]); acc[2][3] = fmaf(a.z, b.w, acc[2][3]);
      acc[3][0] = fmaf(a.w, b.x, acc[3][0]); acc[3][1] = fmaf(a.w, b.y, acc[3][1]);
      acc[3][2] = fmaf(a.w, b.z, acc[3][2]); acc[3][3] = fmaf(a.w, b.w, acc[3][3]);
    }
  }
  #pragma unroll
  for (int i = 0; i < 4; ++i) {
    float4 v = make_float4(acc[i][0], acc[i][1], acc[i][2], acc[i][3]);
    *(float4*)&C[(size_t)(bm + (ty << 2) + i) * N + bn + (tx << 2)] = v;
  }
}

// ---------------- skinny matmul: out[i][j] = sum_k A[i][k]*B[k][j] (+bias)(+relu) ----------------
template<int K, int NCOL, bool BIAS, bool RELU>
__global__ void k_mm_small(const float* __restrict__ A, const float* __restrict__ B,
                           const float* __restrict__ bias, float* __restrict__ out) {
  const int j = threadIdx.x;
  const int i = blockIdx.x * blockDim.y + threadIdx.y;
  const float* ar = A + (size_t)i * K;
  float acc = 0.f;
  #pragma unroll 8
  for (int k = 0; k < K; ++k) acc = fmaf(ar[k], B[(size_t)k * NCOL + j], acc);
  if (BIAS) acc += bias[j];
  if (RELU) acc = fmaxf(acc, 0.f);
  out[(size_t)i * NCOL + j] = acc;
}

// ---------------- launcher ----------------
extern "C" void kernel_launch(void* const* d_in, const int* in_sizes, int n_in,
                              void* d_out, int out_size, void* d_ws, size_t ws_size,
                              hipStream_t stream) {
  const float* x     = (const float*)d_in[0];
  const int*   e00   = (const int*)d_in[1];
  const int*   e01   = (const int*)d_in[2];
  const int*   e10   = (const int*)d_in[3];
  const int*   e11   = (const int*)d_in[4];
  const int*   e12   = (const int*)d_in[5];
  const float* w1    = (const float*)d_in[22];
  const float* bias1 = (const float*)d_in[23];
  const float* w2    = (const float*)d_in[24];
  const float* bias2 = (const float*)d_in[25];
  float* out = (float*)d_out;
  float* ws  = (float*)d_ws;

  float* A0 = ws + OFF_A0;
  float* A1 = ws + OFF_A1;
  float* M0 = ws + OFF_M0;
  float* M1 = ws + OFF_M1;
  float* BT = ws + OFF_BT;
  float* AN = ws + OFF_AN;
  float* H1 = ws + OFF_H1;
  float* H2 = ws + OFF_H2;
  float* H3 = ws + OFF_H3;
  float* DINV = ws + OFF_DINV;
  float* DFLG = ws + OFF_DFLG;
  float* XW1 = ws + OFF_XW1;
  float* HB  = ws + OFF_HB;
  float* HW2 = ws + OFF_HW2;

  // zero adjacency region (5 * NN floats)
  hipMemsetAsync(A0, 0, (size_t)5 * NN * sizeof(float), stream);

  dim3 b256(256), b16(16, 16);
  k_scatter<<<128, b256, 0, stream>>>(e00, A0);
  k_scatter<<<128, b256, 0, stream>>>(e01, A0 + NN);
  k_scatter<<<128, b256, 0, stream>>>(e10, A1);
  k_scatter<<<128, b256, 0, stream>>>(e11, A1 + NN);
  k_scatter<<<128, b256, 0, stream>>>(e12, A1 + 2 * NN);

  // ---- attention block 0 (L=2) ----
  k_conv1_pool<2><<<dim3(32, 32), b16, 0, stream>>>(A0, (const float*)d_in[6], (const float*)d_in[7], H1);
  k_conv2_pool<<<dim3(17, 17), b16, 0, stream>>>(H1, (const float*)d_in[8], (const float*)d_in[9], H2);
  k_tconv1<<<dim3(17, 17), b16, 0, stream>>>(H2, (const float*)d_in[10], (const float*)d_in[11], H3);
  k_tconv2_sig<2><<<dim3(32, 32), b16, 0, stream>>>(H3, (const float*)d_in[12], (const float*)d_in[13], A0);

  // ---- attention block 1 (L=3) ----
  k_conv1_pool<3><<<dim3(32, 32), b16, 0, stream>>>(A1, (const float*)d_in[14], (const float*)d_in[15], H1);
  k_conv2_pool<<<dim3(17, 17), b16, 0, stream>>>(H1, (const float*)d_in[16], (const float*)d_in[17], H2);
  k_tconv1<<<dim3(17, 17), b16, 0, stream>>>(H2, (const float*)d_in[18], (const float*)d_in[19], H3);
  k_tconv2_sig<3><<<dim3(32, 32), b16, 0, stream>>>(H3, (const float*)d_in[20], (const float*)d_in[21], A1);

  // ---- path 0 chain: M0 = norm(att0_0); M0 = norm(M0 @ att0_1) ----
  k_deg<<<1024, b256, 0, stream>>>(A0, DINV, DFLG);
  k_scale<<<4096, b256, 0, stream>>>(A0, DINV, DFLG, M0);
  k_mm1024<<<dim3(16, 16), b256, 0, stream>>>(M0, A0 + NN, BT);
  k_deg<<<1024, b256, 0, stream>>>(BT, DINV, DFLG);
  k_scale<<<4096, b256, 0, stream>>>(BT, DINV, DFLG, M0);

  // ---- path 1 chain: 3 hops ----
  k_deg<<<1024, b256, 0, stream>>>(A1, DINV, DFLG);
  k_scale<<<4096, b256, 0, stream>>>(A1, DINV, DFLG, M1);
  k_mm1024<<<dim3(16, 16), b256, 0, stream>>>(M1, A1 + NN, BT);
  k_deg<<<1024, b256, 0, stream>>>(BT, DINV, DFLG);
  k_scale<<<4096, b256, 0, stream>>>(BT, DINV, DFLG, M1);
  k_mm1024<<<dim3(16, 16), b256, 0, stream>>>(M1, A1 + 2 * NN, BT);
  k_deg<<<1024, b256, 0, stream>>>(BT, DINV, DFLG);
  k_scale<<<4096, b256, 0, stream>>>(BT, DINV, DFLG, M1);

  // ---- combine + final norm ----
  k_max<<<4096, b256, 0, stream>>>(M0, M1, BT);
  k_deg<<<1024, b256, 0, stream>>>(BT, DINV, DFLG);
  k_scale<<<4096, b256, 0, stream>>>(BT, DINV, DFLG, AN);

  // ---- GCN layers ----
  k_mm_small<128, 64, false, false><<<256, dim3(64, 4), 0, stream>>>(x, w1, nullptr, XW1);
  k_mm_small<1024, 64, true, true><<<256, dim3(64, 4), 0, stream>>>(AN, XW1, bias1, HB);
  k_mm_small<64, 32, false, false><<<128, dim3(32, 8), 0, stream>>>(HB, w2, nullptr, HW2);
  k_mm_small<1024, 32, true, false><<<128, dim3(32, 8), 0, stream>>>(AN, HW2, bias2, out);
}